// Round 1
// baseline (401.128 us; speedup 1.0000x reference)
//
#include <hip/hip_runtime.h>
#include <math.h>

#define B_ 32
#define S_ 2048
#define H_ 1024
#define U_ 128

// workspace layout (float offsets, all 16B-aligned)
#define OFF_VPART 0u          // 8*32*1024   = 262144
#define OFF_V     262144u     // 32*1024     = 32768
#define OFF_PM    294912u     // 32*64       = 2048
#define OFF_PL    296960u     // 32*64       = 2048
#define OFF_PCTX  299008u     // 32*64*1024  = 2097152
#define OFF_CTX   2396160u    // 32*1024     = 32768
#define OFF_DPART 2428928u    // 8*32*128    = 32768
// total ~9.9 MB

// ---------------------------------------------------------------------------
// Kernel A: v_part[kc][b][h] = sum over k-chunk of W[h,k] * h_t[b,k]
// grid (16, 8): h-chunks of 64, k-chunks of 128. 256 threads.
__global__ __launch_bounds__(256) void k_vpart(const float* __restrict__ hid,
                                               const float* __restrict__ W,
                                               float* __restrict__ ws) {
    __shared__ float ht[32][128];   // h_t slice for all 32 batches, 16 KB
    const int t  = threadIdx.x;
    const int h0 = blockIdx.x * 64;
    const int k0 = blockIdx.y * 128;
    // coalesced load of h_t[:, k0:k0+128] into LDS (1024 float4s)
    #pragma unroll
    for (int i = 0; i < 4; ++i) {
        int f4 = i * 256 + t;            // 0..1023
        int bl = f4 >> 5;                // batch
        int k4 = f4 & 31;                // float4 within row
        float4 src = *(const float4*)(hid + ((size_t)bl * S_ + (S_ - 1)) * H_ + k0 + k4 * 4);
        *(float4*)&ht[bl][k4 * 4] = src;
    }
    __syncthreads();
    const int hl = t & 63;               // h within chunk (lane -> consecutive rows)
    const int g  = t >> 6;               // batch group (8 batches each)
    const int h  = h0 + hl;
    float acc[8];
    #pragma unroll
    for (int i = 0; i < 8; ++i) acc[i] = 0.f;
    const float4* Wr = (const float4*)(W + (size_t)h * H_ + k0);
    for (int k4 = 0; k4 < 32; ++k4) {
        float4 w4 = Wr[k4];
        float wv[4] = {w4.x, w4.y, w4.z, w4.w};
        #pragma unroll
        for (int c = 0; c < 4; ++c) {
            float w = wv[c];
            int kk = k4 * 4 + c;
            #pragma unroll
            for (int bb = 0; bb < 8; ++bb)
                acc[bb] += w * ht[g * 8 + bb][kk];   // LDS broadcast (uniform addr/wave)
        }
    }
    float* vpart = ws + OFF_VPART;
    const int kc = blockIdx.y;
    #pragma unroll
    for (int bb = 0; bb < 8; ++bb)
        vpart[((size_t)kc * 32 + (g * 8 + bb)) * H_ + h] = acc[bb];  // coalesced in h
}

// Kernel A2: v[b][h] = sum_kc v_part[kc][b][h]
__global__ __launch_bounds__(256) void k_vreduce(float* __restrict__ ws) {
    int e = blockIdx.x * 256 + threadIdx.x;   // < 32768
    const float* vp = ws + OFF_VPART;
    float s = 0.f;
    #pragma unroll
    for (int kc = 0; kc < 8; ++kc) s += vp[kc * 32768 + e];
    ws[OFF_V + e] = s;
}

// ---------------------------------------------------------------------------
// Kernel B: fused score + online softmax + context partial, flash-style.
// One wave owns 32 consecutive s-rows; no LDS, no barriers.
// grid 512 blocks x 256 threads = 2048 waves = 64 waves per batch.
__global__ __launch_bounds__(256) void k_flash(const float* __restrict__ hid,
                                               float* __restrict__ ws) {
    const int t    = threadIdx.x;
    const int lane = t & 63;
    const int wave = t >> 6;
    const int b    = blockIdx.x >> 4;
    const int wi   = (blockIdx.x & 15) * 4 + wave;   // 0..63 within batch
    const int s0   = wi * 32;

    const float* vrow = ws + OFF_V + (size_t)b * H_;
    float4 v4[4], c4[4];
    #pragma unroll
    for (int j = 0; j < 4; ++j) {
        v4[j] = *(const float4*)(vrow + j * 256 + lane * 4);
        c4[j] = make_float4(0.f, 0.f, 0.f, 0.f);
    }
    float m = -INFINITY, l = 0.f;
    const float* base = hid + (size_t)b * S_ * H_;

    for (int r = 0; r < 32; ++r) {
        const float* row = base + (size_t)(s0 + r) * H_;
        float4 h4[4];
        #pragma unroll
        for (int j = 0; j < 4; ++j)
            h4[j] = *(const float4*)(row + j * 256 + lane * 4);   // 1 KB/wave/instr
        float p = 0.f;
        #pragma unroll
        for (int j = 0; j < 4; ++j)
            p += h4[j].x * v4[j].x + h4[j].y * v4[j].y + h4[j].z * v4[j].z + h4[j].w * v4[j].w;
        #pragma unroll
        for (int off = 32; off > 0; off >>= 1) p += __shfl_xor(p, off, 64);
        // p = score[b, s0+r], identical in all 64 lanes
        if (p > m) {                       // wave-uniform branch
            float alpha = __expf(m - p);   // first iter: exp(-inf)=0
            l *= alpha;
            #pragma unroll
            for (int j = 0; j < 4; ++j) {
                c4[j].x *= alpha; c4[j].y *= alpha; c4[j].z *= alpha; c4[j].w *= alpha;
            }
            m = p;
        }
        float e = __expf(p - m);
        l += e;
        #pragma unroll
        for (int j = 0; j < 4; ++j) {
            c4[j].x += e * h4[j].x; c4[j].y += e * h4[j].y;
            c4[j].z += e * h4[j].z; c4[j].w += e * h4[j].w;
        }
    }
    const int pid = b * 64 + wi;
    float* pctx = ws + OFF_PCTX + (size_t)pid * H_;
    #pragma unroll
    for (int j = 0; j < 4; ++j)
        *(float4*)(pctx + j * 256 + lane * 4) = c4[j];
    if (lane == 0) { ws[OFF_PM + pid] = m; ws[OFF_PL + pid] = l; }
}

// ---------------------------------------------------------------------------
// Kernel C: merge the 64 per-wave partials of each batch (exact softmax merge).
// grid 32 x 256; thread owns 4 context columns.
__global__ __launch_bounds__(256) void k_merge(float* __restrict__ ws) {
    const int b = blockIdx.x;
    const int t = threadIdx.x;
    const float* pm = ws + OFF_PM + b * 64;
    const float* pl = ws + OFF_PL + b * 64;
    float M = -INFINITY;
    for (int i = 0; i < 64; ++i) M = fmaxf(M, pm[i]);
    float L = 0.f;
    float4 c = make_float4(0.f, 0.f, 0.f, 0.f);
    const float* pctx = ws + OFF_PCTX + (size_t)b * 64 * H_;
    for (int i = 0; i < 64; ++i) {
        float w = __expf(pm[i] - M);
        L += pl[i] * w;
        float4 x = *(const float4*)(pctx + (size_t)i * H_ + t * 4);
        c.x += w * x.x; c.y += w * x.y; c.z += w * x.z; c.w += w * x.w;
    }
    float inv = 1.f / L;
    c.x *= inv; c.y *= inv; c.z *= inv; c.w *= inv;
    *(float4*)(ws + OFF_CTX + (size_t)b * H_ + t * 4) = c;
}

// ---------------------------------------------------------------------------
// Kernel D1: partial output GEMM: pre=[ctx, h_t] (2048) @ W2 (2048x128), split J.
// grid (8 j-chunks, 32 batches) x 128 threads (one per unit).
__global__ __launch_bounds__(128) void k_out_part(const float* __restrict__ hid,
                                                  const float* __restrict__ W2,
                                                  float* __restrict__ ws) {
    __shared__ float pre[256];
    const int jc = blockIdx.x;
    const int b  = blockIdx.y;
    const int t  = threadIdx.x;
    #pragma unroll
    for (int i = 0; i < 2; ++i) {
        int idx = t * 2 + i;
        int j = jc * 256 + idx;
        float val = (j < 1024)
            ? ws[OFF_CTX + (size_t)b * H_ + j]
            : hid[((size_t)b * S_ + (S_ - 1)) * H_ + (j - 1024)];
        pre[idx] = val;
    }
    __syncthreads();
    float acc = 0.f;
    const float* w2 = W2 + (size_t)jc * 256 * U_ + t;
    #pragma unroll 8
    for (int jj = 0; jj < 256; ++jj)
        acc += pre[jj] * w2[(size_t)jj * U_];     // coalesced across lanes (u)
    ws[OFF_DPART + ((size_t)jc * 32 + b) * U_ + t] = acc;
}

// Kernel D2: reduce J-chunks + tanh.
__global__ __launch_bounds__(256) void k_out_final(const float* __restrict__ ws,
                                                   float* __restrict__ out) {
    int idx = blockIdx.x * 256 + threadIdx.x;    // < 4096
    float s = 0.f;
    #pragma unroll
    for (int jc = 0; jc < 8; ++jc) s += ws[OFF_DPART + jc * 4096 + idx];
    out[idx] = tanhf(s);
}

// ---------------------------------------------------------------------------
extern "C" void kernel_launch(void* const* d_in, const int* in_sizes, int n_in,
                              void* d_out, int out_size, void* d_ws, size_t ws_size,
                              hipStream_t stream) {
    const float* hid = (const float*)d_in[0];   // (32, 2048, 1024) fp32
    const float* W   = (const float*)d_in[1];   // (1024, 1024) fp32
    const float* W2  = (const float*)d_in[2];   // (2048, 128) fp32
    float* ws  = (float*)d_ws;
    float* out = (float*)d_out;                 // (32, 128) fp32

    hipLaunchKernelGGL(k_vpart,     dim3(16, 8), dim3(256), 0, stream, hid, W, ws);
    hipLaunchKernelGGL(k_vreduce,   dim3(128),   dim3(256), 0, stream, ws);
    hipLaunchKernelGGL(k_flash,     dim3(512),   dim3(256), 0, stream, hid, ws);
    hipLaunchKernelGGL(k_merge,     dim3(32),    dim3(256), 0, stream, ws);
    hipLaunchKernelGGL(k_out_part,  dim3(8, 32), dim3(128), 0, stream, hid, W2, ws);
    hipLaunchKernelGGL(k_out_final, dim3(16),    dim3(256), 0, stream, ws, out);
}

// Round 3
// 391.167 us; speedup vs baseline: 1.0255x; 1.0255x over previous
//
#include <hip/hip_runtime.h>
#include <math.h>

#define B_ 32
#define S_ 2048
#define H_ 1024
#define U_ 128

// workspace layout (float offsets, all 16B-aligned)
#define OFF_VPART 0u          // 8*32*1024    = 262144
#define OFF_V     262144u     // 32*1024      = 32768
#define OFF_PM    294912u     // 32*128       = 4096
#define OFF_PL    299008u     // 32*128       = 4096
#define OFF_PCTX  303104u     // 32*128*1024  = 4194304
#define OFF_CTX   4497408u    // 32*1024      = 32768
#define OFF_DPART 4530176u    // 8*32*128     = 32768
// total ~18.3 MB

typedef float vfloat4 __attribute__((ext_vector_type(4)));

static __device__ __forceinline__ float4 ntload4(const float* p) {
    vfloat4 v = __builtin_nontemporal_load((const vfloat4*)p);
    return make_float4(v.x, v.y, v.z, v.w);
}

// ---------------------------------------------------------------------------
// Kernel A: v_part[kc][b][h] = sum over k-chunk of W[h,k] * h_t[b,k]
// grid (16, 8): h-chunks of 64, k-chunks of 128. 256 threads.
__global__ __launch_bounds__(256) void k_vpart(const float* __restrict__ hid,
                                               const float* __restrict__ W,
                                               float* __restrict__ ws) {
    __shared__ float ht[32][128];   // h_t slice for all 32 batches, 16 KB
    const int t  = threadIdx.x;
    const int h0 = blockIdx.x * 64;
    const int k0 = blockIdx.y * 128;
    #pragma unroll
    for (int i = 0; i < 4; ++i) {
        int f4 = i * 256 + t;            // 0..1023
        int bl = f4 >> 5;                // batch
        int k4 = f4 & 31;                // float4 within row
        float4 src = *(const float4*)(hid + ((size_t)bl * S_ + (S_ - 1)) * H_ + k0 + k4 * 4);
        *(float4*)&ht[bl][k4 * 4] = src;
    }
    __syncthreads();
    const int hl = t & 63;               // h within chunk
    const int g  = t >> 6;               // batch group (8 batches each)
    const int h  = h0 + hl;
    float acc[8];
    #pragma unroll
    for (int i = 0; i < 8; ++i) acc[i] = 0.f;
    const float4* Wr = (const float4*)(W + (size_t)h * H_ + k0);
    for (int k4 = 0; k4 < 32; ++k4) {
        float4 w4 = Wr[k4];
        float wv[4] = {w4.x, w4.y, w4.z, w4.w};
        #pragma unroll
        for (int c = 0; c < 4; ++c) {
            float w = wv[c];
            int kk = k4 * 4 + c;
            #pragma unroll
            for (int bb = 0; bb < 8; ++bb)
                acc[bb] += w * ht[g * 8 + bb][kk];
        }
    }
    float* vpart = ws + OFF_VPART;
    const int kc = blockIdx.y;
    #pragma unroll
    for (int bb = 0; bb < 8; ++bb)
        vpart[((size_t)kc * 32 + (g * 8 + bb)) * H_ + h] = acc[bb];
}

// Kernel A2: v[b][h] = sum_kc v_part[kc][b][h]
__global__ __launch_bounds__(256) void k_vreduce(float* __restrict__ ws) {
    int e = blockIdx.x * 256 + threadIdx.x;   // < 32768
    const float* vp = ws + OFF_VPART;
    float s = 0.f;
    #pragma unroll
    for (int kc = 0; kc < 8; ++kc) s += vp[kc * 32768 + e];
    ws[OFF_V + e] = s;
}

// ---------------------------------------------------------------------------
// Kernel B: fused score + online softmax + context partial, flash-style.
// One wave owns 16 consecutive s-rows, 2 rows/iter for ILP (8 float4 in flight).
// grid 1024 blocks x 256 threads = 4096 waves = 128 partials per batch.
// 4 blocks/CU resident -> 4 waves/SIMD.
__global__ __launch_bounds__(256) void k_flash(const float* __restrict__ hid,
                                               float* __restrict__ ws) {
    const int t    = threadIdx.x;
    const int lane = t & 63;
    const int wave = t >> 6;
    const int b    = blockIdx.x >> 5;
    const int wi   = (blockIdx.x & 31) * 4 + wave;   // 0..127 within batch
    const int s0   = wi * 16;

    const float* vrow = ws + OFF_V + (size_t)b * H_;
    float4 v4[4], c4[4];
    #pragma unroll
    for (int j = 0; j < 4; ++j) {
        v4[j] = *(const float4*)(vrow + j * 256 + lane * 4);
        c4[j] = make_float4(0.f, 0.f, 0.f, 0.f);
    }
    float m = -INFINITY, l = 0.f;
    const float* base = hid + ((size_t)b * S_ + s0) * H_ + lane * 4;

    for (int r = 0; r < 16; r += 2) {
        const float* r0 = base + (size_t)r * H_;
        const float* r1 = r0 + H_;
        float4 a4[4], b4[4];
        #pragma unroll
        for (int j = 0; j < 4; ++j) a4[j] = ntload4(r0 + j * 256);
        #pragma unroll
        for (int j = 0; j < 4; ++j) b4[j] = ntload4(r1 + j * 256);
        float p0 = 0.f, p1 = 0.f;
        #pragma unroll
        for (int j = 0; j < 4; ++j) {
            p0 += a4[j].x * v4[j].x + a4[j].y * v4[j].y + a4[j].z * v4[j].z + a4[j].w * v4[j].w;
            p1 += b4[j].x * v4[j].x + b4[j].y * v4[j].y + b4[j].z * v4[j].z + b4[j].w * v4[j].w;
        }
        #pragma unroll
        for (int off = 32; off > 0; off >>= 1) {
            p0 += __shfl_xor(p0, off, 64);
            p1 += __shfl_xor(p1, off, 64);
        }
        float pmax = fmaxf(p0, p1);
        if (pmax > m) {                    // wave-uniform branch
            float alpha = __expf(m - pmax);   // first iter: exp(-inf)=0
            l *= alpha;
            #pragma unroll
            for (int j = 0; j < 4; ++j) {
                c4[j].x *= alpha; c4[j].y *= alpha; c4[j].z *= alpha; c4[j].w *= alpha;
            }
            m = pmax;
        }
        float e0 = __expf(p0 - m), e1 = __expf(p1 - m);
        l += e0 + e1;
        #pragma unroll
        for (int j = 0; j < 4; ++j) {
            c4[j].x += e0 * a4[j].x + e1 * b4[j].x;
            c4[j].y += e0 * a4[j].y + e1 * b4[j].y;
            c4[j].z += e0 * a4[j].z + e1 * b4[j].z;
            c4[j].w += e0 * a4[j].w + e1 * b4[j].w;
        }
    }
    const int pid = b * 128 + wi;
    float* pctx = ws + OFF_PCTX + (size_t)pid * H_;
    #pragma unroll
    for (int j = 0; j < 4; ++j)
        *(float4*)(pctx + j * 256 + lane * 4) = c4[j];
    if (lane == 0) { ws[OFF_PM + pid] = m; ws[OFF_PL + pid] = l; }
}

// ---------------------------------------------------------------------------
// Kernel C: merge the 128 per-wave partials of each batch (exact softmax merge).
// grid (4 col-chunks, 32 batches) x 256; thread owns 1 context column.
__global__ __launch_bounds__(256) void k_merge(float* __restrict__ ws) {
    const int cc = blockIdx.x;
    const int b  = blockIdx.y;
    const int t  = threadIdx.x;
    const float* pm = ws + OFF_PM + b * 128;
    const float* pl = ws + OFF_PL + b * 128;
    float M = -INFINITY;
    #pragma unroll 8
    for (int i = 0; i < 128; ++i) M = fmaxf(M, pm[i]);
    float L = 0.f, c = 0.f;
    const float* pctx = ws + OFF_PCTX + (size_t)b * 128 * H_ + cc * 256 + t;
    #pragma unroll 4
    for (int i = 0; i < 128; ++i) {
        float w = __expf(pm[i] - M);
        L += pl[i] * w;
        c += w * pctx[(size_t)i * H_];
    }
    ws[OFF_CTX + (size_t)b * H_ + cc * 256 + t] = c / L;
}

// ---------------------------------------------------------------------------
// Kernel D1: partial output GEMM: pre=[ctx, h_t] (2048) @ W2 (2048x128), split J.
// grid (8 j-chunks, 32 batches) x 128 threads (one per unit).
__global__ __launch_bounds__(128) void k_out_part(const float* __restrict__ hid,
                                                  const float* __restrict__ W2,
                                                  float* __restrict__ ws) {
    __shared__ float pre[256];
    const int jc = blockIdx.x;
    const int b  = blockIdx.y;
    const int t  = threadIdx.x;
    #pragma unroll
    for (int i = 0; i < 2; ++i) {
        int idx = t * 2 + i;
        int j = jc * 256 + idx;
        float val = (j < 1024)
            ? ws[OFF_CTX + (size_t)b * H_ + j]
            : hid[((size_t)b * S_ + (S_ - 1)) * H_ + (j - 1024)];
        pre[idx] = val;
    }
    __syncthreads();
    float acc = 0.f;
    const float* w2 = W2 + (size_t)jc * 256 * U_ + t;
    #pragma unroll 8
    for (int jj = 0; jj < 256; ++jj)
        acc += pre[jj] * w2[(size_t)jj * U_];
    ws[OFF_DPART + ((size_t)jc * 32 + b) * U_ + t] = acc;
}

// Kernel D2: reduce J-chunks + tanh.
__global__ __launch_bounds__(256) void k_out_final(const float* __restrict__ ws,
                                                   float* __restrict__ out) {
    int idx = blockIdx.x * 256 + threadIdx.x;    // < 4096
    float s = 0.f;
    #pragma unroll
    for (int jc = 0; jc < 8; ++jc) s += ws[OFF_DPART + jc * 4096 + idx];
    out[idx] = tanhf(s);
}

// ---------------------------------------------------------------------------
extern "C" void kernel_launch(void* const* d_in, const int* in_sizes, int n_in,
                              void* d_out, int out_size, void* d_ws, size_t ws_size,
                              hipStream_t stream) {
    const float* hid = (const float*)d_in[0];   // (32, 2048, 1024) fp32
    const float* W   = (const float*)d_in[1];   // (1024, 1024) fp32
    const float* W2  = (const float*)d_in[2];   // (2048, 128) fp32
    float* ws  = (float*)d_ws;
    float* out = (float*)d_out;                 // (32, 128) fp32

    hipLaunchKernelGGL(k_vpart,     dim3(16, 8), dim3(256), 0, stream, hid, W, ws);
    hipLaunchKernelGGL(k_vreduce,   dim3(128),   dim3(256), 0, stream, ws);
    hipLaunchKernelGGL(k_flash,     dim3(1024),  dim3(256), 0, stream, hid, ws);
    hipLaunchKernelGGL(k_merge,     dim3(4, 32), dim3(256), 0, stream, ws);
    hipLaunchKernelGGL(k_out_part,  dim3(8, 32), dim3(128), 0, stream, hid, W2, ws);
    hipLaunchKernelGGL(k_out_final, dim3(16),    dim3(256), 0, stream, ws, out);
}